// Round 6
// baseline (213.959 us; speedup 1.0000x reference)
//
#include <hip/hip_runtime.h>
#include <hip/hip_bf16.h>
#include <math.h>

#define DI   2048      // D_INNER
#define DS   16        // D_STATE
#define DTR  128       // DT_RANK
#define NBATCH 2
#define SEQ  2048
#define ROWS (NBATCH*SEQ)   // 4096
#define NE   (DTR + 2*DS)   // 160
#define NC   32             // chunks along L
#define LC   (SEQ/NC)       // 64
#define KS1  16             // GEMM1 K-split

typedef float f32x4 __attribute__((ext_vector_type(4)));
typedef short s16x8 __attribute__((ext_vector_type(8)));
typedef short s16x4 __attribute__((ext_vector_type(4)));

__device__ inline short f2bf(float f) {
    unsigned u = __builtin_bit_cast(unsigned, f);
    u += 0x7FFFu + ((u >> 16) & 1u);   // RNE
    return (short)(u >> 16);
}

// pack 2 floats -> 2 bf16 (RNE) in one u32 (lowers to v_cvt_pk_bf16_f32)
__device__ inline unsigned pk2(float lo, float hi) {
    union { __hip_bfloat162 h; unsigned u; } cv;
    cv.h = __float22bfloat162_rn(float2{lo, hi});
    return cv.u;
}
// pack (delta_bf16 low | x_bf16 high)
__device__ inline unsigned packdu(short dbf, float xf) {
    return ((unsigned)(unsigned short)f2bf(xf) << 16) | (unsigned)(unsigned short)dbf;
}

// ---------------- cast weights to bf16 ----------------
__global__ __launch_bounds__(256) void k_castw(const float* __restrict__ w,
                                               const float* __restrict__ dtw,
                                               short* __restrict__ wb,
                                               short* __restrict__ dtwb) {
    int i = blockIdx.x*256 + threadIdx.x;     // 4 elems each
    if (i < 81920) {                          // 160*2048/4
        float4 v = ((const float4*)w)[i];
        s16x4 o = { f2bf(v.x), f2bf(v.y), f2bf(v.z), f2bf(v.w) };
        *(s16x4*)(wb + 4*i) = o;
    } else if (i < 147456) {                  // + 2048*128/4
        int j = i - 81920;
        float4 v = ((const float4*)dtw)[j];
        s16x4 o = { f2bf(v.x), f2bf(v.y), f2bf(v.z), f2bf(v.w) };
        *(s16x4*)(dtwb + 4*j) = o;
    }
}

// ---------------- GEMM1: part[ks] = x(bf16 in-reg) @ wb^T — no LDS, K-split 16 ----------------
__global__ __launch_bounds__(256) void k_gemm1(const float* __restrict__ x,
                                               const short* __restrict__ wb,
                                               float* __restrict__ part) {
    const int wave = blockIdx.x*4 + (threadIdx.x >> 6);   // 0..4095
    const int lane = threadIdx.x & 63;
    const int m16 = wave & 255;
    const int ks  = wave >> 8;                            // 0..15
    const int r = lane & 15, g = lane >> 4;
    f32x4 acc[10];
    #pragma unroll
    for (int i = 0; i < 10; i++) acc[i] = (f32x4){0.f,0.f,0.f,0.f};

    const float* xp = x + (size_t)(m16*16 + r)*DI + g*8;
    #pragma unroll
    for (int kk = 0; kk < 4; ++kk) {
        const int k0 = ks*128 + kk*32;
        float4 xa = *(const float4*)(xp + k0);
        float4 xc = *(const float4*)(xp + k0 + 4);
        union { s16x8 v; unsigned u[4]; } af;
        af.u[0] = pk2(xa.x, xa.y);
        af.u[1] = pk2(xa.z, xa.w);
        af.u[2] = pk2(xc.x, xc.y);
        af.u[3] = pk2(xc.z, xc.w);
        const short* bp = wb + (size_t)r*DI + k0 + g*8;
        #pragma unroll
        for (int nf = 0; nf < 10; ++nf) {
            s16x8 bfrag = *(const s16x8*)(bp + (size_t)nf*16*DI);
            acc[nf] = __builtin_amdgcn_mfma_f32_16x16x32_bf16(af.v, bfrag, acc[nf], 0, 0, 0);
        }
    }
    const int orow = m16*16 + g*4;
    #pragma unroll
    for (int nf = 0; nf < 10; ++nf)
        #pragma unroll
        for (int j = 0; j < 4; ++j)
            part[((size_t)ks*ROWS + orow + j)*NE + nf*16 + r] = acc[nf][j];
}

// ---------------- reduce partials, emit dR(bf16) / B / C ----------------
__global__ __launch_bounds__(256) void k_split(const float* __restrict__ part,
                                               short* __restrict__ dRb,
                                               float* __restrict__ Bm,
                                               float* __restrict__ Cm) {
    int i = blockIdx.x*256 + threadIdx.x;
    if (i >= ROWS*NE) return;
    float v = 0.f;
    #pragma unroll
    for (int s = 0; s < KS1; ++s) v += part[(size_t)s*ROWS*NE + i];
    int row = i / NE, e = i - row*NE;
    if (e < DTR)            dRb[(size_t)row*DTR + e] = f2bf(v);
    else if (e < DTR + DS)  Bm[(size_t)row*DS + (e - DTR)] = v;
    else                    Cm[(size_t)row*DS + (e - DTR - DS)] = v;
}

// ---------------- GEMM2: delta(bf16) = softplus(dRb @ dtwb^T + bias) — no LDS ----------------
__global__ __launch_bounds__(256) void k_gemm2(const short* __restrict__ dRb,
                                               const short* __restrict__ dtwb,
                                               const float* __restrict__ bias,
                                               unsigned short* __restrict__ deltab) {
    const int wave = blockIdx.x*4 + (threadIdx.x >> 6);
    const int lane = threadIdx.x & 63;
    const int m16 = wave >> 5, nt = wave & 31;
    const int r = lane & 15, g = lane >> 4;

    s16x8 a[4];
    const short* ap = dRb + (size_t)(m16*16 + r)*DTR + g*8;
    #pragma unroll
    for (int ks = 0; ks < 4; ++ks) a[ks] = *(const s16x8*)(ap + ks*32);

    f32x4 acc[4];
    #pragma unroll
    for (int i = 0; i < 4; i++) acc[i] = (f32x4){0.f,0.f,0.f,0.f};

    #pragma unroll
    for (int nf = 0; nf < 4; ++nf) {
        const short* bp = dtwb + (size_t)(nt*64 + nf*16 + r)*DTR + g*8;
        #pragma unroll
        for (int ks = 0; ks < 4; ++ks) {
            s16x8 b = *(const s16x8*)(bp + ks*32);
            acc[nf] = __builtin_amdgcn_mfma_f32_16x16x32_bf16(a[ks], b, acc[nf], 0, 0, 0);
        }
    }
    const int orow = m16*16 + g*4;
    #pragma unroll
    for (int nf = 0; nf < 4; ++nf) {
        const int col = nt*64 + nf*16 + r;
        const float bb = bias[col];
        #pragma unroll
        for (int j = 0; j < 4; ++j) {
            float v = acc[nf][j] + bb;
            float sp = fmaxf(v, 0.f) + __logf(1.f + __expf(-fabsf(v)));
            deltab[(size_t)(orow + j)*DI + col] = (unsigned short)f2bf(sp);
        }
    }
}

// ---------------- scan pass 1: LDS-staged (packed bf16 delta|x), DS-split x4 ----------------
__global__ __launch_bounds__(256) void k_scan1(const unsigned short* __restrict__ deltab,
                                               const float* __restrict__ x,
                                               const float* __restrict__ Bm,
                                               const float* __restrict__ A_log,
                                               float* __restrict__ aprod,
                                               float* __restrict__ rsum) {
    __shared__ unsigned lxd[LC][64];
    __shared__ float lB[LC][DS];
    const int tid = threadIdx.x;
    const int bb = blockIdx.x & 31;          // d-block 0..31
    const int b  = (blockIdx.x >> 5) & 1;
    const int c  = blockIdx.x >> 6;          // 0..31
    const int d0 = bb*64;
    const int lbase = c*LC;

    // ---- coalesced staging: pack delta(bf16)|x(bf16) into one u32 ----
    {
        const unsigned short* dsrc = deltab + ((size_t)(b*SEQ + lbase))*DI + d0;
        const float*          xsrc = x      + ((size_t)(b*SEQ + lbase))*DI + d0;
        const int row = tid >> 4, col = (tid & 15)*4;
        #pragma unroll
        for (int i = 0; i < 4; i++) {
            s16x4  dv = *(const s16x4*) (dsrc + (size_t)(row + 16*i)*DI + col);
            float4 xv = *(const float4*)(xsrc + (size_t)(row + 16*i)*DI + col);
            uint4 o;
            o.x = packdu(dv[0], xv.x);
            o.y = packdu(dv[1], xv.y);
            o.z = packdu(dv[2], xv.z);
            o.w = packdu(dv[3], xv.w);
            *(uint4*)&lxd[row + 16*i][col] = o;
        }
        const float* bsrc = Bm + ((size_t)(b*SEQ + lbase))*DS;
        *(float4*)&lB[tid >> 2][(tid & 3)*4] = *(const float4*)(bsrc + tid*4);
    }

    const int lane = tid & 63, widx = tid >> 6;
    const int dlow = lane & 15, q = lane >> 4;
    const int dcol = widx*16 + dlow;
    const int d = d0 + dcol;
    const int n0 = 4*q;

    float4 Alg = *(const float4*)(A_log + (size_t)d*DS + n0);
    float An[4] = { -__expf(Alg.x), -__expf(Alg.y), -__expf(Alg.z), -__expf(Alg.w) };
    float ap[4] = {1.f,1.f,1.f,1.f}, r[4] = {0.f,0.f,0.f,0.f};

    __syncthreads();

    #pragma unroll 8
    for (int tt = 0; tt < LC; ++tt) {
        unsigned v = lxd[tt][dcol];
        float dlt = __builtin_bit_cast(float, v << 16);
        float u   = __builtin_bit_cast(float, v & 0xffff0000u);
        float du  = dlt * u;
        float4 bv = *(const float4*)&lB[tt][n0];
        float bbv[4] = {bv.x, bv.y, bv.z, bv.w};
        #pragma unroll
        for (int j = 0; j < 4; ++j) {
            float da = __expf(dlt * An[j]);
            r[j]  = fmaf(da, r[j], du * bbv[j]);
            ap[j] *= da;
        }
    }
    size_t base = (((size_t)c*NBATCH + b)*DI + d)*DS + n0;
    *(float4*)(aprod + base) = (float4){ap[0], ap[1], ap[2], ap[3]};
    *(float4*)(rsum  + base) = (float4){r[0],  r[1],  r[2],  r[3]};
}

// ---------------- middle: sequential combine across chunks ----------------
__global__ __launch_bounds__(256) void k_mid(const float* __restrict__ aprod,
                                             const float* __restrict__ rsum,
                                             float* __restrict__ hin) {
    int gid = blockIdx.x*256 + threadIdx.x;   // B*DI*DS = 65536
    int n = gid & 15;
    int d = (gid >> 4) & (DI-1);
    int b = gid >> 15;
    float h = 0.f;
    for (int c = 0; c < NC; c++) {
        size_t idx = (((size_t)c*NBATCH + b)*DI + d)*DS + n;
        hin[idx] = h;
        h = fmaf(aprod[idx], h, rsum[idx]);
    }
}

// ---------------- scan pass 2: LDS-staged (packed), butterfly-reduce y ----------------
__global__ __launch_bounds__(256) void k_scan2(const unsigned short* __restrict__ deltab,
                                               const float* __restrict__ x,
                                               const float* __restrict__ Bm,
                                               const float* __restrict__ Cm,
                                               const float* __restrict__ A_log,
                                               const float* __restrict__ Dv,
                                               const float* __restrict__ hin,
                                               float* __restrict__ y) {
    __shared__ unsigned lxd[LC][64];
    __shared__ float lB[LC][DS];
    __shared__ float lC[LC][DS];
    const int tid = threadIdx.x;
    const int bb = blockIdx.x & 31;
    const int b  = (blockIdx.x >> 5) & 1;
    const int c  = blockIdx.x >> 6;
    const int d0 = bb*64;
    const int lbase = c*LC;

    // ---- coalesced staging ----
    {
        const unsigned short* dsrc = deltab + ((size_t)(b*SEQ + lbase))*DI + d0;
        const float*          xsrc = x      + ((size_t)(b*SEQ + lbase))*DI + d0;
        const int row = tid >> 4, col = (tid & 15)*4;
        #pragma unroll
        for (int i = 0; i < 4; i++) {
            s16x4  dv = *(const s16x4*) (dsrc + (size_t)(row + 16*i)*DI + col);
            float4 xv = *(const float4*)(xsrc + (size_t)(row + 16*i)*DI + col);
            uint4 o;
            o.x = packdu(dv[0], xv.x);
            o.y = packdu(dv[1], xv.y);
            o.z = packdu(dv[2], xv.z);
            o.w = packdu(dv[3], xv.w);
            *(uint4*)&lxd[row + 16*i][col] = o;
        }
        const float* bsrc = Bm + ((size_t)(b*SEQ + lbase))*DS;
        const float* csrc = Cm + ((size_t)(b*SEQ + lbase))*DS;
        *(float4*)&lB[tid >> 2][(tid & 3)*4] = *(const float4*)(bsrc + tid*4);
        *(float4*)&lC[tid >> 2][(tid & 3)*4] = *(const float4*)(csrc + tid*4);
    }

    const int lane = tid & 63, widx = tid >> 6;
    const int dlow = lane & 15, q = lane >> 4;
    const int dcol = widx*16 + dlow;
    const int d = d0 + dcol;
    const int n0 = 4*q;

    float4 Alg = *(const float4*)(A_log + (size_t)d*DS + n0);
    float An[4] = { -__expf(Alg.x), -__expf(Alg.y), -__expf(Alg.z), -__expf(Alg.w) };
    size_t base = (((size_t)c*NBATCH + b)*DI + d)*DS + n0;
    float4 hv = *(const float4*)(hin + base);
    float h[4] = {hv.x, hv.y, hv.z, hv.w};
    const float Dd = Dv[d];
    float* yp = y + ((size_t)(b*SEQ + lbase))*DI + d;

    __syncthreads();

    #pragma unroll 8
    for (int tt = 0; tt < LC; ++tt) {
        unsigned v = lxd[tt][dcol];
        float dlt = __builtin_bit_cast(float, v << 16);
        float u   = __builtin_bit_cast(float, v & 0xffff0000u);
        float du  = dlt * u;
        float4 bv = *(const float4*)&lB[tt][n0];
        float4 cv = *(const float4*)&lC[tt][n0];
        float bbv[4] = {bv.x, bv.y, bv.z, bv.w};
        float ccv[4] = {cv.x, cv.y, cv.z, cv.w};
        float acc = 0.f;
        #pragma unroll
        for (int j = 0; j < 4; ++j) {
            float da = __expf(dlt * An[j]);
            h[j] = fmaf(da, h[j], du * bbv[j]);
            acc  = fmaf(h[j], ccv[j], acc);
        }
        acc += __shfl_xor(acc, 16);
        acc += __shfl_xor(acc, 32);
        if (q == 0) yp[(size_t)tt*DI] = fmaf(u, Dd, acc);
    }
}

extern "C" void kernel_launch(void* const* d_in, const int* in_sizes, int n_in,
                              void* d_out, int out_size, void* d_ws, size_t ws_size,
                              hipStream_t stream) {
    const float* x     = (const float*)d_in[0];
    const float* A_log = (const float*)d_in[1];
    const float* Dv    = (const float*)d_in[2];
    const float* xpw   = (const float*)d_in[3];
    const float* dtw   = (const float*)d_in[4];
    const float* dtb   = (const float*)d_in[5];
    float* out = (float*)d_out;

    const size_t SCN = (size_t)NC*NBATCH*DS*DI;          // 2,097,152 floats
    const size_t PARTN = (size_t)KS1*ROWS*NE;            // 10,485,760 floats

    float* ws    = (float*)d_ws;
    unsigned short* deltab = (unsigned short*)ws;        // ROWS*DI shorts
    float* unionR= ws + ((size_t)ROWS*DI/2);             // union region start
    float* part  = unionR;                               // PARTN floats (dead after k_split)
    float* aprod = unionR;                               // aliases part
    float* rsum  = aprod + SCN;
    float* hin   = rsum  + SCN;
    float* uend  = unionR + ((3*SCN > PARTN) ? 3*SCN : PARTN);
    float* Bm    = uend;                                 // ROWS*DS
    float* Cm    = Bm + (size_t)ROWS*DS;                 // ROWS*DS
    short* dRb   = (short*)(Cm + (size_t)ROWS*DS);       // ROWS*DTR shorts
    short* wb    = dRb + (size_t)ROWS*DTR;               // 160*2048 shorts
    short* dtwb  = wb  + (size_t)160*2048;               // 2048*128 shorts

    k_castw<<<576, 256, 0, stream>>>(xpw, dtw, wb, dtwb);
    k_gemm1<<<1024, 256, 0, stream>>>(x, wb, part);
    k_split<<<(ROWS*NE + 255)/256, 256, 0, stream>>>(part, dRb, Bm, Cm);
    k_gemm2<<<2048, 256, 0, stream>>>(dRb, dtwb, dtb, deltab);
    k_scan1<<<2048, 256, 0, stream>>>(deltab, x, Bm, A_log, aprod, rsum);
    k_mid<<<256, 256, 0, stream>>>(aprod, rsum, hin);
    k_scan2<<<2048, 256, 0, stream>>>(deltab, x, Bm, Cm, A_log, Dv, hin, out);
}